// Round 1
// 3150.260 us; speedup vs baseline: 1.6186x; 1.6186x over previous
//
#include <hip/hip_runtime.h>
#include <cstdint>
#include <cstddef>

// GPT forward, MI355X. B=2,T=1024,E=2048,H=16,G=4,HS=128,L=4,V=32000,FF=8192.
// bf16 MFMA for all matmuls, fp32 residual stream. Weights are pre-converted
// fp32->bf16 per forward into the dead S-scratch region, so the main GEMM is
// pure bf16 with global_load_lds (width 16) staging, double-buffered LDS,
// and an XCD-chunked block swizzle for W-tile L2 reuse.

typedef unsigned short u16;
typedef unsigned int u32;
typedef __bf16 bf16x8 __attribute__((ext_vector_type(8)));
typedef float f32x4 __attribute__((ext_vector_type(4)));

#define T_SEQ 1024
#define E_DIM 2048
#define NH 16
#define NG 4
#define HS 128
#define FF_DIM 8192
#define NV 32000
#define NL 4

__device__ __forceinline__ u16 f2bf(float f) {
  u32 u = __float_as_uint(f);
  u += 0x7FFFu + ((u >> 16) & 1u);
  return (u16)(u >> 16);
}
__device__ __forceinline__ float bf2f(u16 h) {
  return __uint_as_float(((u32)h) << 16);
}

// async global->LDS, 16B per lane. LDS dest is wave-uniform base + lane*16
// (lane0's pointer is the base; our id layout makes that exactly linear).
__device__ __forceinline__ void gld_lds16(const u16* g, u16* l) {
  __builtin_amdgcn_global_load_lds(
      (const __attribute__((address_space(1))) u32*)g,
      (__attribute__((address_space(3))) u32*)l, 16, 0, 0);
}

// ---------------- fp32 -> bf16 weight conversion (streaming) ----------------
__global__ __launch_bounds__(256) void k_cvt(const float* __restrict__ in,
                                             u16* __restrict__ out, int n8) {
  int i = blockIdx.x * 256 + threadIdx.x;
  int stride = gridDim.x * 256;
  for (; i < n8; i += stride) {
    float4 a = *(const float4*)(in + (size_t)i * 8);
    float4 b = *(const float4*)(in + (size_t)i * 8 + 4);
    uint4 pk;
    pk.x = (u32)f2bf(a.x) | ((u32)f2bf(a.y) << 16);
    pk.y = (u32)f2bf(a.z) | ((u32)f2bf(a.w) << 16);
    pk.z = (u32)f2bf(b.x) | ((u32)f2bf(b.y) << 16);
    pk.w = (u32)f2bf(b.z) | ((u32)f2bf(b.w) << 16);
    *(uint4*)(out + (size_t)i * 8) = pk;
  }
}

// ---------------- embedding gather ----------------
__global__ __launch_bounds__(256) void k_embed(const int* __restrict__ idx,
                                               const float* __restrict__ wte,
                                               float* __restrict__ x) {
  int row = blockIdx.x;           // b*T + t
  int t = threadIdx.x;
  size_t src = (size_t)idx[row] * E_DIM;
  size_t dst = (size_t)row * E_DIM;
  *(float4*)(x + dst + t * 8)     = *(const float4*)(wte + src + t * 8);
  *(float4*)(x + dst + t * 8 + 4) = *(const float4*)(wte + src + t * 8 + 4);
}

// ---------------- rmsnorm -> bf16 ----------------
__global__ __launch_bounds__(256) void k_rmsnorm(const float* __restrict__ x,
                                                 const float* __restrict__ g,
                                                 u16* __restrict__ o) {
  int row = blockIdx.x;
  int t = threadIdx.x;
  const float* xr = x + (size_t)row * E_DIM;
  float4 a = *(const float4*)(xr + t * 8);
  float4 b = *(const float4*)(xr + t * 8 + 4);
  float ss = a.x*a.x + a.y*a.y + a.z*a.z + a.w*a.w
           + b.x*b.x + b.y*b.y + b.z*b.z + b.w*b.w;
#pragma unroll
  for (int off = 32; off; off >>= 1) ss += __shfl_xor(ss, off, 64);
  __shared__ float red[4];
  if ((t & 63) == 0) red[t >> 6] = ss;
  __syncthreads();
  float tot = red[0] + red[1] + red[2] + red[3];
  float sc = rsqrtf(tot * (1.0f / (float)E_DIM) + 1e-5f);
  float4 w0 = *(const float4*)(g + t * 8);
  float4 w1 = *(const float4*)(g + t * 8 + 4);
  uint4 pk;
  pk.x = (u32)f2bf(a.x * sc * w0.x) | ((u32)f2bf(a.y * sc * w0.y) << 16);
  pk.y = (u32)f2bf(a.z * sc * w0.z) | ((u32)f2bf(a.w * sc * w0.w) << 16);
  pk.z = (u32)f2bf(b.x * sc * w1.x) | ((u32)f2bf(b.y * sc * w1.y) << 16);
  pk.w = (u32)f2bf(b.z * sc * w1.z) | ((u32)f2bf(b.w * sc * w1.w) << 16);
  *(uint4*)(o + (size_t)row * E_DIM + t * 8) = pk;
}

// ---------------- main GEMM: C[M,N] (op)= A[M,K](bf16) * W[N,K](bf16)^T ----
// EPI: 0 = store f32, 1 = += into f32 (residual), 2 = gelu -> bf16
// 1-D grid; internal decode with XCD-chunked swizzle (nwg % 8 == 0 for all
// our shapes): blocks with bid%8==x run on XCD x and get a contiguous chunk
// of m-fast work ids -> the 16 m-blocks sharing a W n-tile hit the same L2.
// Staging: global_load_lds 16B with pre-swizzled global source column-chunk
// (u ^ ((r>>1)&3)); ds_read applies the same XOR -> ~2-way LDS conflicts.
template <int EPI>
__global__ __launch_bounds__(256) void k_gemm_bt(const u16* __restrict__ A,
                                                 const u16* __restrict__ B,
                                                 void* __restrict__ Cout,
                                                 int M, int N, int K) {
  __shared__ __align__(16) u16 As[2][128 * 32];
  __shared__ __align__(16) u16 Bs[2][128 * 32];
  const int tid = threadIdx.x;
  const int lane = tid & 63;
  const int w = tid >> 6;

  const int nwg = gridDim.x;
  const int cpx = nwg >> 3;
  const int wg = ((int)blockIdx.x & 7) * cpx + ((int)blockIdx.x >> 3);
  const int m0 = (wg & 15) * 128;   // gm = M/128 = 16 always (M = 2048)
  const int n0 = (wg >> 4) * 128;

  f32x4 acc[4][4] = {};

  auto stage = [&](int buf, int kt) {
#pragma unroll
    for (int p = 0; p < 2; ++p) {
      int id = p * 256 + tid;
      int r = id >> 2, u = (id & 3) ^ ((r >> 1) & 3);
      gld_lds16(A + (size_t)(m0 + r) * K + kt * 32 + u * 8, &As[buf][id * 8]);
    }
#pragma unroll
    for (int p = 0; p < 2; ++p) {
      int id = p * 256 + tid;
      int r = id >> 2, u = (id & 3) ^ ((r >> 1) & 3);
      gld_lds16(B + (size_t)(n0 + r) * K + kt * 32 + u * 8, &Bs[buf][id * 8]);
    }
  };

  stage(0, 0);
  __syncthreads();   // drains vmcnt(0): buf0 ready

  const int nk = K >> 5;
  int cur = 0;
  for (int kt = 0; kt < nk; ++kt) {
    if (kt + 1 < nk) stage(cur ^ 1, kt + 1);  // async prefetch into other buf

    bf16x8 af[4], bfr[4];
    const int lr = lane & 15, lu = lane >> 4;
#pragma unroll
    for (int i = 0; i < 4; ++i) {
      int ra = (w >> 1) * 64 + i * 16 + lr;
      af[i] = *(const bf16x8*)&As[cur][ra * 32 + ((lu ^ ((ra >> 1) & 3)) * 8)];
      int rb = (w & 1) * 64 + i * 16 + lr;
      bfr[i] = *(const bf16x8*)&Bs[cur][rb * 32 + ((lu ^ ((rb >> 1) & 3)) * 8)];
    }
#pragma unroll
    for (int i = 0; i < 4; ++i)
#pragma unroll
      for (int j = 0; j < 4; ++j)
        acc[i][j] = __builtin_amdgcn_mfma_f32_16x16x32_bf16(af[i], bfr[j], acc[i][j], 0, 0, 0);

    __syncthreads();  // waits vmcnt(0): prefetched buf ready; buf[cur] free
    cur ^= 1;
  }

  const int lr = lane & 15, lq = lane >> 4;
#pragma unroll
  for (int i = 0; i < 4; ++i) {
#pragma unroll
    for (int j = 0; j < 4; ++j) {
      int col = n0 + (w & 1) * 64 + j * 16 + lr;
      int rbase = m0 + (w >> 1) * 64 + i * 16 + lq * 4;
#pragma unroll
      for (int r = 0; r < 4; ++r) {
        int row = rbase + r;
        float v = acc[i][j][r];
        if (EPI == 0) {
          ((float*)Cout)[(size_t)row * N + col] = v;
        } else if (EPI == 1) {
          float* C = (float*)Cout;
          size_t o = (size_t)row * N + col;
          C[o] += v;
        } else {
          // tanh-approx gelu (jax default approximate=True)
          float tt = 0.7978845608028654f * (v + 0.044715f * v * v * v);
          tt = fminf(fmaxf(tt, -15.f), 15.f);
          float e2 = __expf(2.f * tt);
          float gel = 0.5f * v * (1.f + (e2 - 1.f) / (e2 + 1.f));
          ((u16*)Cout)[(size_t)row * N + col] = f2bf(gel);
        }
      }
    }
  }
}

// ---------------- rope + qkv split -> bf16 q,k,v ----------------
// q: [B][H][T][HS], k,v: [B][G][T][HS]
__global__ __launch_bounds__(256) void k_rope(const float* __restrict__ qkv,
                                              u16* __restrict__ q,
                                              u16* __restrict__ k,
                                              u16* __restrict__ v) {
  int row = blockIdx.x;  // b*T + t
  int b = row >> 10, t = row & (T_SEQ - 1);
  const float* src = qkv + (size_t)row * 3072;
  int tid = threadIdx.x;
  // q: 1024 rotation pairs
#pragma unroll
  for (int i = 0; i < 4; ++i) {
    int p = tid + (i << 8);
    int h = p >> 6, j = p & 63;
    float inv = exp2f(-(float)j * 0.2076205059304601f);  // 10000^(-j/64)
    float ang = (float)t * inv;
    float c = cosf(ang), s = sinf(ang);
    float x1 = src[h * HS + j], x2 = src[h * HS + j + 64];
    size_t base = ((size_t)(b * NH + h) * T_SEQ + t) * HS;
    q[base + j]      = f2bf(x1 * c - x2 * s);
    q[base + j + 64] = f2bf(x2 * c + x1 * s);
  }
  // k: 256 rotation pairs
  {
    int p = tid;
    int g = p >> 6, j = p & 63;
    float inv = exp2f(-(float)j * 0.2076205059304601f);
    float ang = (float)t * inv;
    float c = cosf(ang), s = sinf(ang);
    float x1 = src[E_DIM + g * HS + j], x2 = src[E_DIM + g * HS + j + 64];
    size_t base = ((size_t)(b * NG + g) * T_SEQ + t) * HS;
    k[base + j]      = f2bf(x1 * c - x2 * s);
    k[base + j + 64] = f2bf(x2 * c + x1 * s);
  }
  // v: plain copy of 512
#pragma unroll
  for (int i = 0; i < 2; ++i) {
    int cdx = tid + (i << 8);
    int g = cdx >> 7, d = cdx & 127;
    size_t base = ((size_t)(b * NG + g) * T_SEQ + t) * HS;
    v[base + d] = f2bf(src[E_DIM + NG * HS + cdx]);
  }
}

// ---------------- attention scores: S = scale * Q K^T (causal tiles) -------
__global__ __launch_bounds__(256) void k_scores(const u16* __restrict__ Q,
                                                const u16* __restrict__ Km,
                                                float* __restrict__ S) {
  int tn = blockIdx.x, tm = blockIdx.y, bh = blockIdx.z;
  if (tn > tm) return;  // fully masked tile
  int b = bh >> 4, hh = bh & 15, g = hh >> 2;
  const u16* Ab = Q + (size_t)bh * T_SEQ * HS + (size_t)tm * 128 * HS;
  const u16* Bb = Km + (size_t)(b * NG + g) * T_SEQ * HS + (size_t)tn * 128 * HS;

  __shared__ __align__(16) u16 As[128 * 32];
  __shared__ __align__(16) u16 Bs[128 * 32];
  const int tid = threadIdx.x, lane = tid & 63, w = tid >> 6;
  f32x4 acc[4][4] = {};
  uint4 ar[2], brv[2];
  auto loadA = [&](int kt) {
#pragma unroll
    for (int p = 0; p < 2; ++p) {
      int id = p * 256 + tid;
      int r = id >> 2, u = id & 3;
      ar[p] = *(const uint4*)(Ab + (size_t)r * HS + kt * 32 + u * 8);
    }
  };
  auto loadB = [&](int kt) {
#pragma unroll
    for (int p = 0; p < 2; ++p) {
      int id = p * 256 + tid;
      int r = id >> 2, u = id & 3;
      brv[p] = *(const uint4*)(Bb + (size_t)r * HS + kt * 32 + u * 8);
    }
  };
  loadA(0); loadB(0);
  for (int kt = 0; kt < 4; ++kt) {
    __syncthreads();
#pragma unroll
    for (int p = 0; p < 2; ++p) {
      int id = p * 256 + tid;
      int r = id >> 2, u = id & 3;
      *(uint4*)&As[r * 32 + (u ^ ((r >> 1) & 3)) * 8] = ar[p];
      *(uint4*)&Bs[r * 32 + (u ^ ((r >> 1) & 3)) * 8] = brv[p];
    }
    __syncthreads();
    if (kt + 1 < 4) { loadA(kt + 1); loadB(kt + 1); }
    bf16x8 af[4], bfr[4];
    const int lr = lane & 15, lu = lane >> 4;
#pragma unroll
    for (int i = 0; i < 4; ++i) {
      int ra = (w >> 1) * 64 + i * 16 + lr;
      af[i] = *(const bf16x8*)&As[ra * 32 + ((lu ^ ((ra >> 1) & 3)) * 8)];
      int rb = (w & 1) * 64 + i * 16 + lr;
      bfr[i] = *(const bf16x8*)&Bs[rb * 32 + ((lu ^ ((rb >> 1) & 3)) * 8)];
    }
#pragma unroll
    for (int i = 0; i < 4; ++i)
#pragma unroll
      for (int j = 0; j < 4; ++j)
        acc[i][j] = __builtin_amdgcn_mfma_f32_16x16x32_bf16(af[i], bfr[j], acc[i][j], 0, 0, 0);
  }
  const float scale = 0.08838834764831845f;  // 1/sqrt(128)
  const int lr = lane & 15, lq = lane >> 4;
  float* Sb = S + (size_t)bh * T_SEQ * T_SEQ;
#pragma unroll
  for (int i = 0; i < 4; ++i)
#pragma unroll
    for (int j = 0; j < 4; ++j)
#pragma unroll
      for (int r = 0; r < 4; ++r) {
        int row = tm * 128 + (w >> 1) * 64 + i * 16 + lq * 4 + r;
        int col = tn * 128 + (w & 1) * 64 + j * 16 + lr;
        Sb[(size_t)row * T_SEQ + col] = scale * acc[i][j][r];
      }
}

// ---------------- causal softmax, in-place fp32 -> bf16 (first half) -------
__global__ __launch_bounds__(256) void k_softmax(float* __restrict__ S) {
  int row = blockIdx.x * 4 + (threadIdx.x >> 6);  // bh*1024 + m
  int lane = threadIdx.x & 63;
  int m = row & (T_SEQ - 1);
  float* src = S + (size_t)row * T_SEQ;
  int len = m + 1;
  int bound = ((m >> 7) + 1) << 7;  // zero-pad up to 128-tile boundary
  float v[16];
  float mx = -1e30f;
#pragma unroll
  for (int i = 0; i < 16; ++i) {
    int c = lane + (i << 6);
    v[i] = (c < len) ? src[c] : -1e30f;
    mx = fmaxf(mx, v[i]);
  }
#pragma unroll
  for (int off = 32; off; off >>= 1) mx = fmaxf(mx, __shfl_xor(mx, off, 64));
  float sum = 0.f;
#pragma unroll
  for (int i = 0; i < 16; ++i) {
    int c = lane + (i << 6);
    v[i] = (c < len) ? __expf(v[i] - mx) : 0.f;
    sum += v[i];
  }
#pragma unroll
  for (int off = 32; off; off >>= 1) sum += __shfl_xor(sum, off, 64);
  float inv = 1.f / sum;
  u16* dst = (u16*)src;
#pragma unroll
  for (int i = 0; i < 16; ++i) {
    int c = lane + (i << 6);
    if (c < bound) dst[c] = (c < len) ? f2bf(v[i] * inv) : (u16)0;
  }
}

// ---------------- P·V -> y (bf16, [B][T][H*HS]) ----------------
// P is bf16 packed in-place in the scores buffer: row stride 2048 u16.
__global__ __launch_bounds__(256) void k_pv(const u16* __restrict__ P,
                                            const u16* __restrict__ V,
                                            u16* __restrict__ y) {
  int tm = blockIdx.x, bh = blockIdx.y;
  int b = bh >> 4, hh = bh & 15, g = hh >> 2;
  const u16* Pb = P + (size_t)bh * T_SEQ * 2048 + (size_t)tm * 128 * 2048;
  const u16* Vb = V + (size_t)(b * NG + g) * T_SEQ * HS;
  int nk = 4 * (tm + 1);  // causal K extent in 32-chunks

  __shared__ __align__(16) u16 As[128 * 32];
  __shared__ __align__(16) u16 Bs[128 * 32];
  const int tid = threadIdx.x, lane = tid & 63, w = tid >> 6;
  f32x4 acc[4][4] = {};
  uint4 ar[2], vr0, vr1;
  auto loadA = [&](int kt) {
#pragma unroll
    for (int p = 0; p < 2; ++p) {
      int id = p * 256 + tid;
      int r = id >> 2, u = id & 3;
      ar[p] = *(const uint4*)(Pb + (size_t)r * 2048 + kt * 32 + u * 8);
    }
  };
  auto loadV = [&](int kt) {
    int kk2 = (tid >> 4) * 2, n0 = (tid & 15) * 8;
    vr0 = *(const uint4*)(Vb + (size_t)(kt * 32 + kk2) * HS + n0);
    vr1 = *(const uint4*)(Vb + (size_t)(kt * 32 + kk2 + 1) * HS + n0);
  };
  loadA(0); loadV(0);
  for (int kt = 0; kt < nk; ++kt) {
    __syncthreads();
#pragma unroll
    for (int p = 0; p < 2; ++p) {
      int id = p * 256 + tid;
      int r = id >> 2, u = id & 3;
      *(uint4*)&As[r * 32 + (u ^ ((r >> 1) & 3)) * 8] = ar[p];
    }
    {  // transpose V[32][128] -> Bs[n][k]
      int kk2 = (tid >> 4) * 2, n0 = (tid & 15) * 8;
      const u16* r0 = (const u16*)&vr0;
      const u16* r1 = (const u16*)&vr1;
      int u = kk2 >> 3, sub = kk2 & 7;
#pragma unroll
      for (int e = 0; e < 8; ++e) {
        int n = n0 + e;
        u32 pv2 = (u32)r0[e] | ((u32)r1[e] << 16);
        *(u32*)&Bs[n * 32 + ((u ^ ((n >> 1) & 3)) * 8) + sub] = pv2;
      }
    }
    __syncthreads();
    if (kt + 1 < nk) { loadA(kt + 1); loadV(kt + 1); }
    bf16x8 af[4], bfr[4];
    const int lr = lane & 15, lu = lane >> 4;
#pragma unroll
    for (int i = 0; i < 4; ++i) {
      int ra = (w >> 1) * 64 + i * 16 + lr;
      af[i] = *(const bf16x8*)&As[ra * 32 + ((lu ^ ((ra >> 1) & 3)) * 8)];
      int rb = (w & 1) * 64 + i * 16 + lr;
      bfr[i] = *(const bf16x8*)&Bs[rb * 32 + ((lu ^ ((rb >> 1) & 3)) * 8)];
    }
#pragma unroll
    for (int i = 0; i < 4; ++i)
#pragma unroll
      for (int j = 0; j < 4; ++j)
        acc[i][j] = __builtin_amdgcn_mfma_f32_16x16x32_bf16(af[i], bfr[j], acc[i][j], 0, 0, 0);
  }
  const int lr = lane & 15, lq = lane >> 4;
#pragma unroll
  for (int i = 0; i < 4; ++i)
#pragma unroll
    for (int j = 0; j < 4; ++j)
#pragma unroll
      for (int r = 0; r < 4; ++r) {
        int row = tm * 128 + (w >> 1) * 64 + i * 16 + lq * 4 + r;  // t
        int col = (w & 1) * 64 + j * 16 + lr;                      // d
        y[(size_t)(b * T_SEQ + row) * E_DIM + hh * HS + col] = f2bf(acc[i][j][r]);
      }
}

// ---------------- launch ----------------
extern "C" void kernel_launch(void* const* d_in, const int* in_sizes, int n_in,
                              void* d_out, int out_size, void* d_ws, size_t ws_size,
                              hipStream_t stream) {
  const int* idx = (const int*)d_in[0];
  const float* wte = (const float*)d_in[1];
  const float* qkv_w = (const float*)d_in[2];
  const float* attn_proj_w = (const float*)d_in[3];
  const float* fc_w = (const float*)d_in[4];
  const float* mlp_proj_w = (const float*)d_in[5];
  const float* norm1_w = (const float*)d_in[6];
  const float* norm2_w = (const float*)d_in[7];
  const float* lnf_w = (const float*)d_in[8];
  const float* lm_head_w = (const float*)d_in[9];
  float* out = (float*)d_out;

  const int BT = 2 * T_SEQ;  // 2048 rows
  char* ws = (char*)d_ws;
  float* x = (float*)ws;              ws += (size_t)BT * E_DIM * 4;        // residual f32
  u16* xn = (u16*)ws;                 ws += (size_t)BT * E_DIM * 2;        // normed bf16
  float* qkv = (float*)ws;            ws += (size_t)BT * 3072 * 4;
  u16* q = (u16*)ws;                  ws += (size_t)2 * NH * T_SEQ * HS * 2;
  u16* kb = (u16*)ws;                 ws += (size_t)2 * NG * T_SEQ * HS * 2;
  u16* vb = (u16*)ws;                 ws += (size_t)2 * NG * T_SEQ * HS * 2;
  float* S = (float*)ws;              ws += (size_t)2 * NH * T_SEQ * T_SEQ * 4;  // scores f32 / P bf16 in place
  u16* y = (u16*)ws;                  ws += (size_t)BT * E_DIM * 2;
  u16* hbuf = (u16*)ws;               ws += (size_t)BT * FF_DIM * 2;

  // bf16 weight scratch aliases S (134 MB >= lm_head's 131 MB); each weight
  // matrix is dead-converted into it just before its GEMM, at points where S
  // holds no live data (P is consumed by k_pv before the attn_proj convert).
  u16* Wb = (u16*)S;

  auto cvt = [&](const float* src, size_t n) {
    int n8 = (int)(n >> 3);
    int blocks = (n8 + 255) >> 8;
    if (blocks > 4096) blocks = 4096;
    k_cvt<<<blocks, 256, 0, stream>>>(src, Wb, n8);
  };

  k_embed<<<BT, 256, 0, stream>>>(idx, wte, x);

  for (int l = 0; l < NL; ++l) {
    k_rmsnorm<<<BT, 256, 0, stream>>>(x, norm1_w + (size_t)l * E_DIM, xn);
    cvt(qkv_w + (size_t)l * 3072 * E_DIM, (size_t)3072 * E_DIM);
    k_gemm_bt<0><<<16 * 24, 256, 0, stream>>>(xn, Wb, qkv, BT, 3072, E_DIM);
    k_rope<<<BT, 256, 0, stream>>>(qkv, q, kb, vb);
    k_scores<<<dim3(8, 8, 32), 256, 0, stream>>>(q, kb, S);
    k_softmax<<<(2 * NH * T_SEQ) / 4, 256, 0, stream>>>(S);
    k_pv<<<dim3(8, 32), 256, 0, stream>>>((const u16*)S, vb, y);
    cvt(attn_proj_w + (size_t)l * E_DIM * E_DIM, (size_t)E_DIM * E_DIM);
    k_gemm_bt<1><<<16 * 16, 256, 0, stream>>>(y, Wb, x, BT, E_DIM, E_DIM);
    k_rmsnorm<<<BT, 256, 0, stream>>>(x, norm2_w + (size_t)l * E_DIM, xn);
    cvt(fc_w + (size_t)l * FF_DIM * E_DIM, (size_t)FF_DIM * E_DIM);
    k_gemm_bt<2><<<16 * 64, 256, 0, stream>>>(xn, Wb, hbuf, BT, FF_DIM, E_DIM);
    cvt(mlp_proj_w + (size_t)l * E_DIM * FF_DIM, (size_t)E_DIM * FF_DIM);
    k_gemm_bt<1><<<16 * 16, 256, 0, stream>>>(hbuf, Wb, x, BT, E_DIM, FF_DIM);
  }

  k_rmsnorm<<<BT, 256, 0, stream>>>(x, lnf_w, xn);
  cvt(lm_head_w, (size_t)NV * E_DIM);
  k_gemm_bt<0><<<16 * 250, 256, 0, stream>>>(xn, Wb, out, BT, NV, E_DIM);
}